// Round 10
// baseline (258.913 us; speedup 1.0000x reference)
//
#include <hip/hip_runtime.h>

#define NPOS   65536      // 16*16*16*16 positions
#define CDIM   256
#define KCODES 512
#define ZTOT   16777216   // 16*256*16*16*16
#define IDX_OFF (ZTOT + 1)
#define TAU    2.0e-3f
#define GL_CAP 16384
#define CHUNK_BYTES 16384

// ws layout (float idx): [0]=loss acc; int[1]=refine count; [64..576)=cb_sq f32;
// [66112..131648) = cb bf16 in MFMA-fragment order (ushort[131072]);
// int[132096..) = candidate slots: 10 ints each {n, nc, cand[8]}, GL_CAP slots
#define WS_CBSQ 64
#define WS_CBBF 66112
#define WS_GLI  132096
#define NC_FULL 0x7fff

using bf16x8 = __attribute__((ext_vector_type(8))) short;
using f32x4  = __attribute__((ext_vector_type(4))) float;

__device__ __forceinline__ unsigned short f2bf(float f) {
    unsigned int u = __float_as_uint(f);
    return (unsigned short)((u + 0x7fffu + ((u >> 16) & 1u)) >> 16);
}

// numpy pairwise sum-of-squares, f32, contraction-proof (verified r3)
__device__ __forceinline__ float np_pw128_sq(const float* a) {
    float r[8];
    #pragma unroll
    for (int j = 0; j < 8; ++j) r[j] = __fmul_rn(a[j], a[j]);
    #pragma unroll 1
    for (int i = 8; i < 128; i += 8) {
        #pragma unroll
        for (int j = 0; j < 8; ++j)
            r[j] = __fadd_rn(r[j], __fmul_rn(a[i + j], a[i + j]));
    }
    return __fadd_rn(__fadd_rn(__fadd_rn(r[0], r[1]), __fadd_rn(r[2], r[3])),
                     __fadd_rn(__fadd_rn(r[4], r[5]), __fadd_rn(r[6], r[7])));
}

// Merged: fragment-order bf16 codebook (verified r8) + np-pairwise cb_sq
// (verified r3, chain-parallel form verified in refine r6). Block = one row.
__global__ void vq_cvtprep(const float* __restrict__ cb, float* __restrict__ ws) {
    const int k = blockIdx.x;        // 512 blocks = codebook rows
    const int c = threadIdx.x;       // 256 channels
    __shared__ float row[256];
    __shared__ float chres[16];
    const float v = cb[(size_t)k * CDIM + c];
    row[c] = v;
    unsigned short* cbf2 = (unsigned short*)(ws + WS_CBBF);
    const int kt = c >> 5, g = (c & 31) >> 3, j = c & 7;
    cbf2[((((k >> 4) * 8 + kt) * 64) + g * 16 + (k & 15)) * 8 + j] = f2bf(v);
    if (k == 0 && c == 0) { ws[0] = 0.0f; ((int*)ws)[1] = 0; }
    __syncthreads();
    if (c < 16) {
        const float* a = &row[(c & 8) * 16];     // c<8: ch 0..127; else 128..255
        const int jj = c & 7;
        float r = __fmul_rn(a[jj], a[jj]);
        #pragma unroll 1
        for (int m = 1; m < 16; ++m)
            r = __fadd_rn(r, __fmul_rn(a[jj + 8 * m], a[jj + 8 * m]));
        chres[c] = r;
    }
    __syncthreads();
    if (c == 0) {
        float h0 = __fadd_rn(__fadd_rn(__fadd_rn(chres[0], chres[1]), __fadd_rn(chres[2], chres[3])),
                             __fadd_rn(__fadd_rn(chres[4], chres[5]), __fadd_rn(chres[6], chres[7])));
        float h1 = __fadd_rn(__fadd_rn(__fadd_rn(chres[8], chres[9]), __fadd_rn(chres[10], chres[11])),
                             __fadd_rn(__fadd_rn(chres[12], chres[13]), __fadd_rn(chres[14], chres[15])));
        ws[WS_CBSQ + k] = __fadd_rn(h0, h1);
    }
}

// Screening: block = 64 rows x 512 codes. Each wave: 16 rows x ALL codes,
// acc fully retained (128 regs -> AGPR). B staged LDS chunk-wise (32 codes =
// 16 KB contiguous in fragment order) with async-split: issue loads -> MFMA
// current -> ds_write next -> sync. Scores bit-identical to r7/r8/r9.
// launch_bounds(256,2): r8 lesson — capping registers below need spills acc.
__launch_bounds__(256, 2)
__global__ void vq_screen(const float* __restrict__ z,
                          float* __restrict__ ws,
                          float* __restrict__ out) {
    const int t  = threadIdx.x;
    const int w  = t >> 6;
    const int l  = t & 63;
    const int g  = l >> 4;
    const int c0 = l & 15;
    const int m0 = blockIdx.x * 64;
    const int b  = m0 >> 12;
    const int s0 = m0 & 4095;
    int* wsi = (int*)ws;

    __shared__ __align__(16) char ldsB[2][CHUNK_BYTES];   // 32 KB
    __shared__ float cbsq_s[KCODES];
    __shared__ int   ccnt[64];
    __shared__ int   candk[64][8];

    cbsq_s[t]       = ws[WS_CBSQ + t];
    cbsq_s[256 + t] = ws[WS_CBSQ + 256 + t];
    if (t < 64) ccnt[t] = 0;

    const char* gB = (const char*)(ws + WS_CBBF);

    // issue chunk-0 loads early
    float4 st[4];
    {
        const char* src = gB + t * 16;
        #pragma unroll
        for (int i = 0; i < 4; ++i)
            st[i] = *(const float4*)(src + i * 4096);
    }

    // A fragments: 64 scalar z loads -> bf16 (one-time; deep unroll)
    const float* zb = z + (size_t)b * 1048576 + s0 + w * 16 + c0;
    bf16x8 afr[8];
    #pragma unroll
    for (int kt = 0; kt < 8; ++kt) {
        bf16x8 a;
        #pragma unroll
        for (int j = 0; j < 8; ++j)
            a[j] = (short)f2bf(zb[(size_t)(kt * 32 + g * 8 + j) * 4096]);
        afr[kt] = a;
    }

    // write chunk 0
    {
        char* dst = &ldsB[0][t * 16];
        #pragma unroll
        for (int i = 0; i < 4; ++i)
            *(float4*)(dst + i * 4096) = st[i];
    }
    __syncthreads();

    f32x4 acc[16][2];
    #pragma unroll
    for (int c = 0; c < 16; ++c) {
        acc[c][0] = (f32x4){0.f, 0.f, 0.f, 0.f};
        acc[c][1] = (f32x4){0.f, 0.f, 0.f, 0.f};
    }

    #pragma unroll
    for (int c = 0; c < 16; ++c) {
        const int buf = c & 1;
        if (c < 15) {                         // issue next-chunk loads (in flight during MFMA)
            const char* src = gB + (c + 1) * CHUNK_BYTES + t * 16;
            #pragma unroll
            for (int i = 0; i < 4; ++i)
                st[i] = *(const float4*)(src + i * 4096);
        }
        #pragma unroll
        for (int p = 0; p < 2; ++p) {
            #pragma unroll
            for (int kt = 0; kt < 8; ++kt) {
                const bf16x8 bfr = *(const bf16x8*)(&ldsB[buf][(p * 8 + kt) * 1024 + l * 16]);
                acc[c][p] = __builtin_amdgcn_mfma_f32_16x16x32_bf16(afr[kt], bfr, acc[c][p], 0, 0, 0);
            }
        }
        if (c < 15) {                         // land next chunk
            char* dst = &ldsB[buf ^ 1][t * 16];
            #pragma unroll
            for (int i = 0; i < 4; ++i)
                *(float4*)(dst + i * 4096) = st[i];
        }
        __syncthreads();
    }

    // ---- per-lane running argmin over retained scores ----
    float v1[4]; int i1[4];
    #pragma unroll
    for (int r = 0; r < 4; ++r) { v1[r] = 3.4028235e38f; i1[r] = 0; }
    #pragma unroll
    for (int c = 0; c < 16; ++c) {
        #pragma unroll
        for (int p = 0; p < 2; ++p) {
            const int k = c * 32 + p * 16 + c0;
            const float cq = cbsq_s[k];
            #pragma unroll
            for (int r = 0; r < 4; ++r) {
                const float s = fmaf(-2.0f, acc[c][p][r], cq);
                if (s < v1[r]) { v1[r] = s; i1[r] = k; }   // k ascending -> np first-min
            }
        }
    }
    // 16-lane butterfly with np tie-break
    #pragma unroll
    for (int r = 0; r < 4; ++r) {
        #pragma unroll
        for (int m = 1; m < 16; m <<= 1) {
            float pv = __shfl_xor(v1[r], m, 64);
            int   pi = __shfl_xor(i1[r], m, 64);
            if (pv < v1[r] || (pv == v1[r] && pi < i1[r])) { v1[r] = pv; i1[r] = pi; }
        }
    }
    // ---- exact candidate re-scan (same condition as r9: s < fv1 + TAU) ----
    #pragma unroll
    for (int c = 0; c < 16; ++c) {
        #pragma unroll
        for (int p = 0; p < 2; ++p) {
            const int k = c * 32 + p * 16 + c0;
            const float cq = cbsq_s[k];
            #pragma unroll
            for (int r = 0; r < 4; ++r) {
                const float s = fmaf(-2.0f, acc[c][p][r], cq);
                if (s < v1[r] + TAU) {
                    const int lrow = w * 16 + g * 4 + r;
                    int pos = atomicAdd(&ccnt[lrow], 1);
                    if (pos < 8) candk[lrow][pos] = k;
                }
            }
        }
    }
    // same-wave LDS atomics complete in order -> c0==0 lanes read & emit
    if (c0 == 0) {
        #pragma unroll
        for (int r = 0; r < 4; ++r) {
            const int lrow = w * 16 + g * 4 + r;
            const int n = m0 + lrow;
            out[IDX_OFF + n] = (float)i1[r];     // provisional (final unless refined)
            const int nc = ccnt[lrow];
            if (nc > 1) {
                int slot = atomicAdd(wsi + 1, 1);
                if (slot < GL_CAP) {
                    int* gl = wsi + WS_GLI + slot * 10;
                    gl[0] = n;
                    gl[1] = (nc > 8) ? NC_FULL : nc;
                    #pragma unroll
                    for (int q = 0; q < 8; ++q)
                        gl[2 + q] = (q < nc && q < 8) ? candk[lrow][q] : 0;
                }
            }
        }
    }
}

// Exact np-replica on candidate codes only. One block per flagged row. (r6)
__global__ void vq_refine(const float* __restrict__ z,
                          const float* __restrict__ cb,
                          float* __restrict__ ws,
                          float* __restrict__ out) {
    int* wsi = (int*)ws;
    const int cnt = min(wsi[1], GL_CAP);
    const int t   = threadIdx.x;
    const int wid = t >> 6;
    const int l   = t & 63;

    __shared__ __align__(16) float zs[260];
    __shared__ float chres[16];
    __shared__ float zsq_sh;
    __shared__ float wbv[4];
    __shared__ int   wbi[4];

    for (int slot = blockIdx.x; slot < cnt; slot += gridDim.x) {
        __syncthreads();
        const int* gl = wsi + WS_GLI + slot * 10;
        const int n  = gl[0];
        const int nc = gl[1];
        const size_t zb = (size_t)(n >> 12) * 1048576 + (size_t)(n & 4095);
        zs[t] = z[zb + (size_t)t * 4096];
        __syncthreads();

        if (t < 16) {
            const float* a = &zs[(t & 8) * 16];
            const int j = t & 7;
            float r = __fmul_rn(a[j], a[j]);
            #pragma unroll 1
            for (int m = 1; m < 16; ++m)
                r = __fadd_rn(r, __fmul_rn(a[j + 8 * m], a[j + 8 * m]));
            chres[t] = r;
        }
        __syncthreads();
        if (t == 0) {
            float h0 = __fadd_rn(__fadd_rn(__fadd_rn(chres[0], chres[1]), __fadd_rn(chres[2], chres[3])),
                                 __fadd_rn(__fadd_rn(chres[4], chres[5]), __fadd_rn(chres[6], chres[7])));
            float h1 = __fadd_rn(__fadd_rn(__fadd_rn(chres[8], chres[9]), __fadd_rn(chres[10], chres[11])),
                                 __fadd_rn(__fadd_rn(chres[12], chres[13]), __fadd_rn(chres[14], chres[15])));
            zsq_sh = __fadd_rn(h0, h1);
        }
        __syncthreads();
        const float zsq = zsq_sh;
        const float4 zl = *(const float4*)&zs[4 * l];

        float bv = 3.4028235e38f;
        int   bi = 0x7fffffff;
        if (nc != NC_FULL) {
            for (int ci = wid; ci < nc; ci += 4) {
                const int k = gl[2 + ci];
                const float4 e = *(const float4*)(cb + (size_t)k * CDIM + 4 * l);
                double d = (double)e.x * (double)zl.x + (double)e.y * (double)zl.y
                         + (double)e.z * (double)zl.z + (double)e.w * (double)zl.w;
                #pragma unroll
                for (int m = 1; m < 64; m <<= 1)
                    d += __shfl_xor(d, m, 64);
                const float dist = __fsub_rn(__fadd_rn(zsq, ws[WS_CBSQ + k]),
                                             __fmul_rn(2.0f, (float)d));
                if (dist < bv || (dist == bv && k < bi)) { bv = dist; bi = k; }
            }
        } else {
            for (int k = wid; k < KCODES; k += 4) {
                const float4 e = *(const float4*)(cb + (size_t)k * CDIM + 4 * l);
                double d = (double)e.x * (double)zl.x + (double)e.y * (double)zl.y
                         + (double)e.z * (double)zl.z + (double)e.w * (double)zl.w;
                #pragma unroll
                for (int m = 1; m < 64; m <<= 1)
                    d += __shfl_xor(d, m, 64);
                const float dist = __fsub_rn(__fadd_rn(zsq, ws[WS_CBSQ + k]),
                                             __fmul_rn(2.0f, (float)d));
                if (dist < bv || (dist == bv && k < bi)) { bv = dist; bi = k; }
            }
        }
        if (l == 0) { wbv[wid] = bv; wbi[wid] = bi; }
        __syncthreads();
        if (t == 0) {
            float v = wbv[0]; int i = wbi[0];
            #pragma unroll
            for (int ww = 1; ww < 4; ++ww) {
                if (wbv[ww] < v || (wbv[ww] == v && wbi[ww] < i)) { v = wbv[ww]; i = wbi[ww]; }
            }
            out[IDX_OFF + n] = (float)i;
        }
    }
}

// z_q gather + loss: block = 32 consecutive positions x 256 channels.
__launch_bounds__(256, 4)
__global__ void vq_gather(const float* __restrict__ z,
                          const float* __restrict__ cb,
                          float* __restrict__ out,
                          float* __restrict__ ws) {
    __shared__ int   sidx[32];
    __shared__ float lcb[32][257];
    const int t  = threadIdx.x;
    const int n0 = blockIdx.x * 32;
    const int b  = n0 >> 12;
    const int s0 = n0 & 4095;

    if (t < 32) sidx[t] = (int)out[IDX_OFF + n0 + t];
    __syncthreads();

    #pragma unroll 4
    for (int e = t; e < 32 * 256; e += 256) {
        const int r = e >> 8, c = e & 255;
        lcb[r][c] = cb[(size_t)sidx[r] * CDIM + c];
    }
    __syncthreads();

    float acc = 0.0f;
    const int sl = t & 31, cg = t >> 5;
    const size_t base = (size_t)b * 1048576 + (size_t)s0 + sl;
    #pragma unroll 4
    for (int i = 0; i < 32; ++i) {
        const int c = i * 8 + cg;
        const size_t o = base + (size_t)c * 4096;
        float v  = lcb[sl][c];
        float zv = z[o];
        out[o] = v;
        float df = v - zv;
        acc += df * df;
    }

    #pragma unroll
    for (int off = 32; off > 0; off >>= 1)
        acc += __shfl_down(acc, off, 64);
    __shared__ float wsum[4];
    const int lane = t & 63, wid = t >> 6;
    if (lane == 0) wsum[wid] = acc;
    __syncthreads();
    if (t == 0)
        atomicAdd(&ws[0], wsum[0] + wsum[1] + wsum[2] + wsum[3]);
}

__global__ void vq_fin(const float* __restrict__ ws, float* __restrict__ out) {
    if (threadIdx.x == 0)
        out[ZTOT] = 1.25f * ws[0] / (float)ZTOT;
}

extern "C" void kernel_launch(void* const* d_in, const int* in_sizes, int n_in,
                              void* d_out, int out_size, void* d_ws, size_t ws_size,
                              hipStream_t stream) {
    const float* z  = (const float*)d_in[0];
    const float* cb = (const float*)d_in[1];
    float* out = (float*)d_out;
    float* ws  = (float*)d_ws;

    vq_cvtprep<<<512, 256, 0, stream>>>(cb, ws);
    vq_screen<<<NPOS / 64, 256, 0, stream>>>(z, ws, out);
    vq_refine<<<2048, 256, 0, stream>>>(z, cb, ws, out);
    vq_gather<<<NPOS / 32, 256, 0, stream>>>(z, cb, out, ws);
    vq_fin<<<1, 64, 0, stream>>>(ws, out);
}

// Round 11
// 166.873 us; speedup vs baseline: 1.5516x; 1.5516x over previous
//
#include <hip/hip_runtime.h>

#define NPOS   65536      // 16*16*16*16 positions
#define CDIM   256
#define KCODES 512
#define ZTOT   16777216   // 16*256*16*16*16
#define IDX_OFF (ZTOT + 1)
#define TAU    2.0e-3f
#define GL_CAP 16384

// ws layout (float idx): [0]=loss acc; int[1]=refine count; [64..576)=cb_sq f32;
// [66112..131648) = cb bf16 in MFMA-fragment order (ushort[131072]);
// int[132096..) = candidate slots: 10 ints each {n, nc, cand[8]}, GL_CAP slots
#define WS_CBSQ 64
#define WS_CBBF 66112
#define WS_GLI  132096
#define NC_FULL 0x7fff

using bf16x8 = __attribute__((ext_vector_type(8))) short;
using f32x4  = __attribute__((ext_vector_type(4))) float;

__device__ __forceinline__ unsigned short f2bf(float f) {
    unsigned int u = __float_as_uint(f);
    return (unsigned short)((u + 0x7fffu + ((u >> 16) & 1u)) >> 16);
}

// numpy pairwise sum-of-squares, f32, contraction-proof (verified r3)
__device__ __forceinline__ float np_pw128_sq(const float* a) {
    float r[8];
    #pragma unroll
    for (int j = 0; j < 8; ++j) r[j] = __fmul_rn(a[j], a[j]);
    #pragma unroll 1
    for (int i = 8; i < 128; i += 8) {
        #pragma unroll
        for (int j = 0; j < 8; ++j)
            r[j] = __fadd_rn(r[j], __fmul_rn(a[i + j], a[i + j]));
    }
    return __fadd_rn(__fadd_rn(__fadd_rn(r[0], r[1]), __fadd_rn(r[2], r[3])),
                     __fadd_rn(__fadd_rn(r[4], r[5]), __fadd_rn(r[6], r[7])));
}

// Merged: fragment-order bf16 codebook (verified r8) + np-pairwise cb_sq
// (verified r3/r6). Block = one codebook row.
__global__ void vq_cvtprep(const float* __restrict__ cb, float* __restrict__ ws) {
    const int k = blockIdx.x;        // 512 blocks = codebook rows
    const int c = threadIdx.x;       // 256 channels
    __shared__ float row[256];
    __shared__ float chres[16];
    const float v = cb[(size_t)k * CDIM + c];
    row[c] = v;
    unsigned short* cbf2 = (unsigned short*)(ws + WS_CBBF);
    const int kt = c >> 5, g = (c & 31) >> 3, j = c & 7;
    cbf2[((((k >> 4) * 8 + kt) * 64) + g * 16 + (k & 15)) * 8 + j] = f2bf(v);
    if (k == 0 && c == 0) { ws[0] = 0.0f; ((int*)ws)[1] = 0; }
    __syncthreads();
    if (c < 16) {
        const float* a = &row[(c & 8) * 16];
        const int jj = c & 7;
        float r = __fmul_rn(a[jj], a[jj]);
        #pragma unroll 1
        for (int m = 1; m < 16; ++m)
            r = __fadd_rn(r, __fmul_rn(a[jj + 8 * m], a[jj + 8 * m]));
        chres[c] = r;
    }
    __syncthreads();
    if (c == 0) {
        float h0 = __fadd_rn(__fadd_rn(__fadd_rn(chres[0], chres[1]), __fadd_rn(chres[2], chres[3])),
                             __fadd_rn(__fadd_rn(chres[4], chres[5]), __fadd_rn(chres[6], chres[7])));
        float h1 = __fadd_rn(__fadd_rn(__fadd_rn(chres[8], chres[9]), __fadd_rn(chres[10], chres[11])),
                             __fadd_rn(__fadd_rn(chres[12], chres[13]), __fadd_rn(chres[14], chres[15])));
        ws[WS_CBSQ + k] = __fadd_rn(h0, h1);
    }
}

// A-tile staging write: channel c, quad q, 4 rows -> fragment-order LDS
__device__ __forceinline__ void stw(unsigned short A[2][8][64][8], int nb,
                                    int c, int q, float4 v) {
    const int kt = c >> 5, gg = (c & 31) >> 3, j = c & 7;
    unsigned short* d = &A[nb][kt][gg * 16 + q * 4][j];
    d[0]  = f2bf(v.x);
    d[8]  = f2bf(v.y);
    d[16] = f2bf(v.z);
    d[24] = f2bf(v.w);
}

// Screening v3: persistent-B. 512 threads (8 waves); wave w holds codes
// [w*64,w*64+64) as 32 register-resident fragments (loaded ONCE). Block
// loops over 16 row-tiles (16 rows each); A double-buffered in LDS with
// async-split prefetch. Scores bit-identical to r7-r10 (same fragment
// mapping, same kt-ascending MFMA chain, same fmaf/TAU/tie-break logic).
__launch_bounds__(512, 2)
__global__ void vq_screen(const float* __restrict__ z,
                          float* __restrict__ ws,
                          float* __restrict__ out) {
    const int t  = threadIdx.x;
    const int w  = t >> 6;
    const int l  = t & 63;
    const int g  = l >> 4;
    const int c0 = l & 15;
    int* wsi = (int*)ws;
    const unsigned short* cbf2 = (const unsigned short*)(ws + WS_CBBF);

    __shared__ unsigned short ldsA[2][8][64][8];   // 16 KB (2 x 8 KB tiles)
    __shared__ float cbsq_s[KCODES];
    __shared__ float red_v[8][16];
    __shared__ int   red_i[8][16];
    __shared__ float fv1[16];
    __shared__ int   ccnt[16];
    __shared__ int   candk[16][8];

    cbsq_s[t] = ws[WS_CBSQ + t];       // 512 threads = 512 entries
    if (t < 16) ccnt[t] = 0;

    // persistent B fragments: 4 code-groups x 8 kt = 128 VGPR, loaded once
    bf16x8 bfr[4][8];
    #pragma unroll
    for (int p = 0; p < 4; ++p)
        #pragma unroll
        for (int kt = 0; kt < 8; ++kt)
            bfr[p][kt] = *(const bf16x8*)(cbf2 + ((((w * 4 + p) * 8 + kt) * 64 + l) << 3));

    const int base = blockIdx.x * 256;                 // 256 rows per block
    const float* zB = z + (size_t)(base >> 12) * 1048576;
    const int c1 = t >> 2, q = t & 3;                  // staging role

    // stage tile 0
    {
        const float* zb = zB + (base & 4095);
        float4 a0 = *(const float4*)(zb + (size_t)c1 * 4096 + q * 4);
        float4 a1 = *(const float4*)(zb + (size_t)(c1 + 128) * 4096 + q * 4);
        stw(ldsA, 0, c1, q, a0);
        stw(ldsA, 0, c1 + 128, q, a1);
    }
    __syncthreads();

    #pragma unroll 1
    for (int i = 0; i < 16; ++i) {
        const int buf = i & 1;
        const int m0  = base + i * 16;

        // issue next-tile A loads early (consumed by ds_write before B3)
        float4 p0, p1;
        if (i < 15) {
            const float* zb = zB + ((m0 + 16) & 4095);
            p0 = *(const float4*)(zb + (size_t)c1 * 4096 + q * 4);
            p1 = *(const float4*)(zb + (size_t)(c1 + 128) * 4096 + q * 4);
        }

        f32x4 acc[4];
        #pragma unroll
        for (int p = 0; p < 4; ++p) acc[p] = (f32x4){0.f, 0.f, 0.f, 0.f};

        #pragma unroll
        for (int kt = 0; kt < 8; ++kt) {
            const bf16x8 a = *(const bf16x8*)&ldsA[buf][kt][l][0];
            acc[0] = __builtin_amdgcn_mfma_f32_16x16x32_bf16(a, bfr[0][kt], acc[0], 0, 0, 0);
            acc[1] = __builtin_amdgcn_mfma_f32_16x16x32_bf16(a, bfr[1][kt], acc[1], 0, 0, 0);
            acc[2] = __builtin_amdgcn_mfma_f32_16x16x32_bf16(a, bfr[2][kt], acc[2], 0, 0, 0);
            acc[3] = __builtin_amdgcn_mfma_f32_16x16x32_bf16(a, bfr[3][kt], acc[3], 0, 0, 0);
        }

        // per-lane argmin (k ascending via p), then 16-lane butterfly
        float v1[4]; int i1[4];
        #pragma unroll
        for (int r = 0; r < 4; ++r) { v1[r] = 3.4028235e38f; i1[r] = 0; }
        #pragma unroll
        for (int p = 0; p < 4; ++p) {
            const int k = w * 64 + p * 16 + c0;
            const float cq = cbsq_s[k];
            #pragma unroll
            for (int r = 0; r < 4; ++r) {
                const float s = fmaf(-2.0f, acc[p][r], cq);
                if (s < v1[r]) { v1[r] = s; i1[r] = k; }
            }
        }
        #pragma unroll
        for (int r = 0; r < 4; ++r) {
            #pragma unroll
            for (int m = 1; m < 16; m <<= 1) {
                float pv = __shfl_xor(v1[r], m, 64);
                int   pi = __shfl_xor(i1[r], m, 64);
                if (pv < v1[r] || (pv == v1[r] && pi < i1[r])) { v1[r] = pv; i1[r] = pi; }
            }
        }
        if (c0 == 0) {
            #pragma unroll
            for (int r = 0; r < 4; ++r) {
                red_v[w][g * 4 + r] = v1[r];
                red_i[w][g * 4 + r] = i1[r];
            }
        }
        __syncthreads();                               // B1

        float gv = 0.f; int gi = 0;
        if (t < 16) {
            gv = red_v[0][t]; gi = red_i[0][t];
            #pragma unroll
            for (int ww = 1; ww < 8; ++ww) {
                const float pv = red_v[ww][t];
                const int   pi = red_i[ww][t];
                if (pv < gv || (pv == gv && pi < gi)) { gv = pv; gi = pi; }
            }
            fv1[t] = gv;
        }
        __syncthreads();                               // B2

        // candidate rescan vs global row-min (identical semantics to r9/r10)
        #pragma unroll
        for (int p = 0; p < 4; ++p) {
            const int k = w * 64 + p * 16 + c0;
            const float cq = cbsq_s[k];
            #pragma unroll
            for (int r = 0; r < 4; ++r) {
                const float s = fmaf(-2.0f, acc[p][r], cq);
                const int row = g * 4 + r;
                if (s < fv1[row] + TAU) {
                    int pos = atomicAdd(&ccnt[row], 1);
                    if (pos < 8) candk[row][pos] = k;
                }
            }
        }
        if (i < 15) {                                  // land next A tile
            stw(ldsA, buf ^ 1, c1, q, p0);
            stw(ldsA, buf ^ 1, c1 + 128, q, p1);
        }
        __syncthreads();                               // B3

        if (t < 16) {
            const int n = m0 + t;
            out[IDX_OFF + n] = (float)gi;              // provisional/final
            const int nc = ccnt[t];
            if (nc > 1) {
                int slot = atomicAdd(wsi + 1, 1);
                if (slot < GL_CAP) {
                    int* gl = wsi + WS_GLI + slot * 10;
                    gl[0] = n;
                    gl[1] = (nc > 8) ? NC_FULL : nc;
                    #pragma unroll
                    for (int qq = 0; qq < 8; ++qq)
                        gl[2 + qq] = (qq < nc && qq < 8) ? candk[t][qq] : 0;
                }
            }
            ccnt[t] = 0;                               // reset for next iter
        }
    }
}

// Exact np-replica on candidate codes only. One block per flagged row. (r6)
__global__ void vq_refine(const float* __restrict__ z,
                          const float* __restrict__ cb,
                          float* __restrict__ ws,
                          float* __restrict__ out) {
    int* wsi = (int*)ws;
    const int cnt = min(wsi[1], GL_CAP);
    const int t   = threadIdx.x;
    const int wid = t >> 6;
    const int l   = t & 63;

    __shared__ __align__(16) float zs[260];
    __shared__ float chres[16];
    __shared__ float zsq_sh;
    __shared__ float wbv[4];
    __shared__ int   wbi[4];

    for (int slot = blockIdx.x; slot < cnt; slot += gridDim.x) {
        __syncthreads();
        const int* gl = wsi + WS_GLI + slot * 10;
        const int n  = gl[0];
        const int nc = gl[1];
        const size_t zb = (size_t)(n >> 12) * 1048576 + (size_t)(n & 4095);
        zs[t] = z[zb + (size_t)t * 4096];
        __syncthreads();

        if (t < 16) {
            const float* a = &zs[(t & 8) * 16];
            const int j = t & 7;
            float r = __fmul_rn(a[j], a[j]);
            #pragma unroll 1
            for (int m = 1; m < 16; ++m)
                r = __fadd_rn(r, __fmul_rn(a[j + 8 * m], a[j + 8 * m]));
            chres[t] = r;
        }
        __syncthreads();
        if (t == 0) {
            float h0 = __fadd_rn(__fadd_rn(__fadd_rn(chres[0], chres[1]), __fadd_rn(chres[2], chres[3])),
                                 __fadd_rn(__fadd_rn(chres[4], chres[5]), __fadd_rn(chres[6], chres[7])));
            float h1 = __fadd_rn(__fadd_rn(__fadd_rn(chres[8], chres[9]), __fadd_rn(chres[10], chres[11])),
                                 __fadd_rn(__fadd_rn(chres[12], chres[13]), __fadd_rn(chres[14], chres[15])));
            zsq_sh = __fadd_rn(h0, h1);
        }
        __syncthreads();
        const float zsq = zsq_sh;
        const float4 zl = *(const float4*)&zs[4 * l];

        float bv = 3.4028235e38f;
        int   bi = 0x7fffffff;
        if (nc != NC_FULL) {
            for (int ci = wid; ci < nc; ci += 4) {
                const int k = gl[2 + ci];
                const float4 e = *(const float4*)(cb + (size_t)k * CDIM + 4 * l);
                double d = (double)e.x * (double)zl.x + (double)e.y * (double)zl.y
                         + (double)e.z * (double)zl.z + (double)e.w * (double)zl.w;
                #pragma unroll
                for (int m = 1; m < 64; m <<= 1)
                    d += __shfl_xor(d, m, 64);
                const float dist = __fsub_rn(__fadd_rn(zsq, ws[WS_CBSQ + k]),
                                             __fmul_rn(2.0f, (float)d));
                if (dist < bv || (dist == bv && k < bi)) { bv = dist; bi = k; }
            }
        } else {
            for (int k = wid; k < KCODES; k += 4) {
                const float4 e = *(const float4*)(cb + (size_t)k * CDIM + 4 * l);
                double d = (double)e.x * (double)zl.x + (double)e.y * (double)zl.y
                         + (double)e.z * (double)zl.z + (double)e.w * (double)zl.w;
                #pragma unroll
                for (int m = 1; m < 64; m <<= 1)
                    d += __shfl_xor(d, m, 64);
                const float dist = __fsub_rn(__fadd_rn(zsq, ws[WS_CBSQ + k]),
                                             __fmul_rn(2.0f, (float)d));
                if (dist < bv || (dist == bv && k < bi)) { bv = dist; bi = k; }
            }
        }
        if (l == 0) { wbv[wid] = bv; wbi[wid] = bi; }
        __syncthreads();
        if (t == 0) {
            float v = wbv[0]; int i = wbi[0];
            #pragma unroll
            for (int ww = 1; ww < 4; ++ww) {
                if (wbv[ww] < v || (wbv[ww] == v && wbi[ww] < i)) { v = wbv[ww]; i = wbi[ww]; }
            }
            out[IDX_OFF + n] = (float)i;
        }
    }
}

// z_q gather + loss: block = 32 consecutive positions x 256 channels.
__launch_bounds__(256, 4)
__global__ void vq_gather(const float* __restrict__ z,
                          const float* __restrict__ cb,
                          float* __restrict__ out,
                          float* __restrict__ ws) {
    __shared__ int   sidx[32];
    __shared__ float lcb[32][257];
    const int t  = threadIdx.x;
    const int n0 = blockIdx.x * 32;
    const int b  = n0 >> 12;
    const int s0 = n0 & 4095;

    if (t < 32) sidx[t] = (int)out[IDX_OFF + n0 + t];
    __syncthreads();

    #pragma unroll 4
    for (int e = t; e < 32 * 256; e += 256) {
        const int r = e >> 8, c = e & 255;
        lcb[r][c] = cb[(size_t)sidx[r] * CDIM + c];
    }
    __syncthreads();

    float acc = 0.0f;
    const int sl = t & 31, cg = t >> 5;
    const size_t base = (size_t)b * 1048576 + (size_t)s0 + sl;
    #pragma unroll 4
    for (int i = 0; i < 32; ++i) {
        const int c = i * 8 + cg;
        const size_t o = base + (size_t)c * 4096;
        float v  = lcb[sl][c];
        float zv = z[o];
        out[o] = v;
        float df = v - zv;
        acc += df * df;
    }

    #pragma unroll
    for (int off = 32; off > 0; off >>= 1)
        acc += __shfl_down(acc, off, 64);
    __shared__ float wsum[4];
    const int lane = t & 63, wid = t >> 6;
    if (lane == 0) wsum[wid] = acc;
    __syncthreads();
    if (t == 0)
        atomicAdd(&ws[0], wsum[0] + wsum[1] + wsum[2] + wsum[3]);
}

__global__ void vq_fin(const float* __restrict__ ws, float* __restrict__ out) {
    if (threadIdx.x == 0)
        out[ZTOT] = 1.25f * ws[0] / (float)ZTOT;
}

extern "C" void kernel_launch(void* const* d_in, const int* in_sizes, int n_in,
                              void* d_out, int out_size, void* d_ws, size_t ws_size,
                              hipStream_t stream) {
    const float* z  = (const float*)d_in[0];
    const float* cb = (const float*)d_in[1];
    float* out = (float*)d_out;
    float* ws  = (float*)d_ws;

    vq_cvtprep<<<512, 256, 0, stream>>>(cb, ws);
    vq_screen<<<NPOS / 256, 512, 0, stream>>>(z, ws, out);
    vq_refine<<<2048, 256, 0, stream>>>(z, cb, ws, out);
    vq_gather<<<NPOS / 32, 256, 0, stream>>>(z, cb, out, ws);
    vq_fin<<<1, 64, 0, stream>>>(ws, out);
}